// Round 19
// baseline (127.919 us; speedup 1.0000x reference)
//
#include <hip/hip_runtime.h>
#include <stdint.h>

// ---------------------------------------------------------------------------
// H=512, N=8, B=4, T=1024.
// bf16 GEMM (weight folds): 128x128 tile, BK=64, 4 waves, 16x16x32 MFMA,
// global_load_lds width-16 staging, pre-swizzled source + XOR-swizzled
// ds_read (T2 both-sides), single-buffer 2-barrier loop.
// INT8 GEMMs: mfma_i32_16x16x64_i8, 128x128 tiles, K-permuted operands
// (both sides; integer-exact), packed dword epilogue stores.
//   - PU & LG (this round): PERSISTENT-B kernels.  B panel (128 rows x 512 K
//     = 64 KB) staged ONCE into resident LDS; block loops 4 by-tiles staging
//     only the 8 KB A chunk per 128-byte K-tile.  LDS 80 KB -> 2 blocks/CU.
//     Cuts staged bytes ~2.6x; per-drain payload halves.
//   - F1 / FF: unchanged 2-operand staging template (r15 structure).
//   - T1 XCD-chunked flat-block remap on all i8 grids.
// Quant scales: x ->2^-5, W~/W^ ->2^-11, P ->2^-11 (invs folded),
//   U ->2^-7, y1 ->2^-5, Wf1T/Wf2T ->2^-10, f1 ->2^-6.
// Algebraic folds (per-head H x H): logits_a = x (Wq_a Wk_a^T) x^T -> W~_a;
//   (d o V)@Wo = sum_a d_a x(Wv_a Wo_a) -> W^_a; d_a folded into LN1.
// Logits epilogue: exp + row-sums + diagonal.  Wf2 split-K x4 bf16 partials.
// Fused prologue `prep` (converts + x quant + transposes + dsum zero).
// ---------------------------------------------------------------------------

#define LN_EPS 1e-5f

typedef __attribute__((ext_vector_type(8))) short short8;
typedef __attribute__((ext_vector_type(4))) float f32x4;
typedef __attribute__((ext_vector_type(4))) int int4v;

__device__ __forceinline__ unsigned short f2bf(float f) {
    unsigned int u = __float_as_uint(f);
    u = (u + 0x7fffu + ((u >> 16) & 1u)) >> 16;
    return (unsigned short)u;
}
__device__ __forceinline__ float bf2f(unsigned short h) {
    return __uint_as_float(((unsigned int)h) << 16);
}
__device__ __forceinline__ signed char q8(float v, float s) {
    int q = (int)rintf(v * s);
    q = q > 127 ? 127 : (q < -127 ? -127 : q);
    return (signed char)q;
}
// permuted position of original within-64 index w
__device__ __forceinline__ int pperm(int w) {
    return (w & ~63) + ((w & 15) << 2) + ((w >> 4) & 3);
}

__device__ __forceinline__ void llds16(const void* g, void* l) {
    __builtin_amdgcn_global_load_lds(
        (const __attribute__((address_space(1))) void*)g,
        (__attribute__((address_space(3))) void*)l, 16, 0, 0);
}

// ---------------------------------------------------------------------------
// PREP: fused prologue.  Flat-bid ranges:
//  [0,3072) convert Wq/Wk/Wv->bf16; [3072,5120) quant_x_perm;
//  [5120,7168) transpose Wo->bf16; [7168,8192) transpose Wf1->i8;
//  [8192,9216) transpose Wf2->i8 (perm dst); [9216,9344) zero dsum.
// ---------------------------------------------------------------------------
__global__ __launch_bounds__(256) void prep(
    const float* __restrict__ Wq, const float* __restrict__ Wk,
    const float* __restrict__ Wv, unsigned short* __restrict__ Wqb,
    const float* __restrict__ x, signed char* __restrict__ xq,
    const float* __restrict__ Wo, unsigned short* __restrict__ WoT,
    const float* __restrict__ Wf1, signed char* __restrict__ Wf1Tq,
    const float* __restrict__ Wf2, signed char* __restrict__ Wf2Tq,
    float* __restrict__ dsum) {
    __shared__ float tile[32][33];
    const int bid = blockIdx.x;
    const int tid = threadIdx.x;

    if (bid < 3072) {
        const int y = bid >> 10;
        const int idx = (bid & 1023) * 256 + tid;
        const float* src = (y == 0) ? Wq : (y == 1) ? Wk : Wv;
        float4 a = ((const float4*)src)[idx * 2];
        float4 b = ((const float4*)src)[idx * 2 + 1];
        uint4 o;
        o.x = (unsigned int)f2bf(a.x) | ((unsigned int)f2bf(a.y) << 16);
        o.y = (unsigned int)f2bf(a.z) | ((unsigned int)f2bf(a.w) << 16);
        o.z = (unsigned int)f2bf(b.x) | ((unsigned int)f2bf(b.y) << 16);
        o.w = (unsigned int)f2bf(b.z) | ((unsigned int)f2bf(b.w) << 16);
        ((uint4*)(Wqb + (long)y * 2097152))[idx] = o;
    } else if (bid < 5120) {
        const int idx = (bid - 3072) * 256 + tid;
        const int t = idx >> 7;
        const int rem = idx & 127;
        const int g = rem >> 4, lr = rem & 15;
        const long rb = (long)t * 512 + g * 64;
        unsigned int o = 0;
#pragma unroll
        for (int n = 0; n < 4; ++n)
            o |= (unsigned int)(unsigned char)q8(x[rb + n * 16 + lr], 32.f)
                 << (8 * n);
        *(unsigned int*)(xq + rb + lr * 4) = o;
    } else if (bid < 7168) {
        const int r = bid - 5120;
        const int bx = r & 15, by = r >> 4;
        const int tx = tid & 31, ty = tid >> 5;
        const int r0 = by * 32, c0 = bx * 32;
        const int R = 4096, C = 512;
#pragma unroll
        for (int k = 0; k < 4; ++k)
            tile[ty + k * 8][tx] = Wo[(long)(r0 + ty + k * 8) * C + c0 + tx];
        __syncthreads();
#pragma unroll
        for (int k = 0; k < 4; ++k)
            WoT[(long)(c0 + ty + k * 8) * R + r0 + tx] =
                f2bf(tile[tx][ty + k * 8]);
    } else if (bid < 8192) {
        const int r = bid - 7168;
        const int bx = r & 63, by = r >> 6;
        const int tx = tid & 31, ty = tid >> 5;
        const int r0 = by * 32, c0 = bx * 32;
        const int R = 512, C = 2048;
#pragma unroll
        for (int k = 0; k < 4; ++k)
            tile[ty + k * 8][tx] = Wf1[(long)(r0 + ty + k * 8) * C + c0 + tx];
        __syncthreads();
#pragma unroll
        for (int k = 0; k < 4; ++k)
            Wf1Tq[(long)(c0 + ty + k * 8) * R + (r0 + tx)] =
                q8(tile[tx][ty + k * 8], 1024.f);
    } else if (bid < 9216) {
        const int r = bid - 8192;
        const int bx = r & 15, by = r >> 4;
        const int tx = tid & 31, ty = tid >> 5;
        const int r0 = by * 32, c0 = bx * 32;
        const int R = 2048, C = 512;
#pragma unroll
        for (int k = 0; k < 4; ++k)
            tile[ty + k * 8][tx] = Wf2[(long)(r0 + ty + k * 8) * C + c0 + tx];
        __syncthreads();
#pragma unroll
        for (int k = 0; k < 4; ++k) {
            const int rr = r0 + tx;
            Wf2Tq[(long)(c0 + ty + k * 8) * R + pperm(rr)] =
                q8(tile[tx][ty + k * 8], 1024.f);
        }
    } else {
        const int idx = (bid - 9216) * 256 + tid;
        dsum[idx] = 0.f;
    }
}

// ---------------------------------------------------------------------------
// bf16 MFMA GEMM (weight folds).  DUAL: bz = f*8+a.  Output i8, cols
// K-permuted + dword-packed.
// ---------------------------------------------------------------------------
__global__ __launch_bounds__(256) void gemm_fold(
    const unsigned short* __restrict__ A,
    const unsigned short* __restrict__ Bt,
    const unsigned short* __restrict__ A2,
    const unsigned short* __restrict__ B2,
    signed char* __restrict__ Cv,
    int N, int K, int lda, int ldb,
    long aBatch, long bBatch, long cBatch) {
    __shared__ unsigned short As[128 * 64];
    __shared__ unsigned short Bs[128 * 64];

    const int bx = blockIdx.x, by = blockIdx.y, bz = blockIdx.z;
    const int tid = threadIdx.x;
    const int wid = tid >> 6;
    const int lane = tid & 63;
    const int lr = lane & 15;
    const int kg = lane >> 4;
    const int wr = wid >> 1;
    const int wc = wid & 1;
    const int row0 = by * 128;
    const int col0 = bx * 128;

    const int zf = bz >> 3, za = bz & 7;
    const unsigned short* Ab = (zf ? A2 : A) + (long)za * aBatch;
    const unsigned short* Bb = (zf ? B2 : Bt) + (long)za * bBatch;
    const long cOff = (long)bz * cBatch;

    const int l8 = lane >> 3;
    const int cs = ((lane & 7) ^ l8) * 8;
    unsigned short* ldsA = &As[wid * 2048];
    unsigned short* ldsB = &Bs[wid * 2048];
    const unsigned short* gA = Ab + (long)(row0 + wid * 32 + l8) * lda + cs;
    const unsigned short* gB = Bb + (long)(col0 + wid * 32 + l8) * ldb + cs;

    const int lr7 = lr & 7;
    const int uS0 = ((0 + kg) ^ lr7) * 8;
    const int uS1 = ((4 + kg) ^ lr7) * 8;

    f32x4 acc[4][4];
#pragma unroll
    for (int m = 0; m < 4; ++m)
#pragma unroll
        for (int n = 0; n < 4; ++n)
#pragma unroll
            for (int j = 0; j < 4; ++j) acc[m][n][j] = 0.f;

    for (int kk = 0; kk < K; kk += 64) {
        __syncthreads();
#pragma unroll
        for (int i = 0; i < 4; ++i) {
            llds16(gA + (long)i * 8 * lda + kk, ldsA + i * 512);
            llds16(gB + (long)i * 8 * ldb + kk, ldsB + i * 512);
        }
        __syncthreads();
        short8 a[4][2], b[4][2];
#pragma unroll
        for (int m = 0; m < 4; ++m) {
            const int ro = (wr * 64 + m * 16 + lr) * 64;
            a[m][0] = *(const short8*)&As[ro + uS0];
            a[m][1] = *(const short8*)&As[ro + uS1];
        }
#pragma unroll
        for (int n = 0; n < 4; ++n) {
            const int ro = (wc * 64 + n * 16 + lr) * 64;
            b[n][0] = *(const short8*)&Bs[ro + uS0];
            b[n][1] = *(const short8*)&Bs[ro + uS1];
        }
#pragma unroll
        for (int s = 0; s < 2; ++s)
#pragma unroll
            for (int m = 0; m < 4; ++m)
#pragma unroll
                for (int n = 0; n < 4; ++n)
                    acc[m][n] = __builtin_amdgcn_mfma_f32_16x16x32_bf16(
                        a[m][s], b[n][s], acc[m][n], 0, 0, 0);
    }

    const int gbase = col0 + wc * 64 + lr * 4;
#pragma unroll
    for (int m = 0; m < 4; ++m) {
        const int grow = row0 + wr * 64 + m * 16 + kg * 4;
#pragma unroll
        for (int j = 0; j < 4; ++j) {
            unsigned int o = 0;
#pragma unroll
            for (int n = 0; n < 4; ++n)
                o |= (unsigned int)(unsigned char)q8(acc[m][n][j], 2048.f)
                     << (8 * n);
            *(unsigned int*)(Cv + cOff + (long)(grow + j) * N + gbase) = o;
        }
    }
}

// ---------------------------------------------------------------------------
// PERSISTENT-B INT8 GEMM (PU and LG).
// LDS (dynamic 80 KB): Bs[128][512] resident panel + As[128][128] per-K-tile.
// Block computes 4 by-tiles for one (bx, ·, bz); B staged once.
// IM=0 PU : grid (32,8,2).  A=xq8 [4096][512]p (lda 512);
//           B=Wallq8 + bz*4096*512 + col0*512.  by = byh*4+byl (0..31).
//           bz0 -> Pq8 (q8 x invs2048), bz1 -> U i8 (q8 x128).
// IM=1 LG : grid (8,2,32).  b=bz>>3, a=bz&7;
//           A=Pq8 + b*1024*4096 + a*512 (lda 4096);
//           B=xq8 + b*1024*512 + col0*512.  by = byh*4+byl (0..7).
//           epilogue per by: exp(acc*2^-16) -> dsum/ddiag.
// Swizzle: B panel row r, K-chunk kt: stored unit u3 holds global unit
// u3^(r&7) (source pre-swizzled, LDS linear); reads use ((s*4+kg)^(lr&7)).
// A chunk staged exactly as the r15-verified pattern.
// ---------------------------------------------------------------------------
template <int IM>
__global__ __launch_bounds__(256) void gemm_pers(
    const signed char* __restrict__ Abase,
    const signed char* __restrict__ Bbase,
    signed char* __restrict__ o8,
    float* __restrict__ dsum, float* __restrict__ ddiag,
    float invs2048) {
    extern __shared__ signed char lds[];
    signed char* Bs = lds;            // 65536 B
    signed char* As = lds + 65536;    // 16384 B

    // T1 XCD-chunked remap (512 blocks, multiple of 8)
    const unsigned gx = gridDim.x, gy = gridDim.y;
    const unsigned nwg = gx * gy * gridDim.z;
    unsigned flat = blockIdx.x + gx * (blockIdx.y + gy * blockIdx.z);
    flat = (flat & 7u) * (nwg >> 3) + (flat >> 3);
    const int bx = flat % gx;
    const int byh = (flat / gx) % gy;
    const int bz = flat / (gx * gy);

    const int tid = threadIdx.x;
    const int wid = tid >> 6;
    const int lane = tid & 63;
    const int lr = lane & 15;
    const int kg = lane >> 4;
    const int wr = wid >> 1;
    const int wc = wid & 1;
    const int col0 = bx * 128;

    int lda;
    const signed char* Ab;
    const signed char* Bb;
    if (IM == 0) {
        lda = 512;
        Ab = Abase;
        Bb = Bbase + (long)bz * (4096 * 512) + (long)col0 * 512;
    } else {
        lda = 4096;
        const int b = bz >> 3, a = bz & 7;
        Ab = Abase + (long)b * (1024 * 4096) + a * 512;
        Bb = Bbase + (long)b * (1024 * 512) + (long)col0 * 512;
    }

    // ---- stage resident B panel: per wave 32 rows x 512B = 16 calls of 1KB
    {
        const int l5 = lane >> 5;        // row parity within call
        const int u5 = lane & 31;        // 16B unit within 512B row
        const int ktS = u5 >> 3, u3 = u5 & 7;
#pragma unroll
        for (int i = 0; i < 16; ++i) {
            const int r = wid * 32 + i * 2 + l5;   // panel row 0..127
            const signed char* g =
                Bb + (long)r * 512 + ktS * 128 + ((u3 ^ (r & 7)) * 16);
            llds16(g, Bs + (wid * 32 + i * 2) * 512);
        }
    }

    // A staging lane constants (identical to r15 pattern)
    const int l8 = lane >> 3;
    const int cs = ((lane & 7) ^ l8) * 16;
    signed char* ldsA = As + wid * 4096;

    const int lr7 = lr & 7;
    const int uS0 = ((0 + kg) ^ lr7) * 16;
    const int uS1 = ((4 + kg) ^ lr7) * 16;

    const int nby = (IM == 0) ? 32 : 8;  // total by tiles (loop covers 4)
    (void)nby;

#pragma unroll 1
    for (int byl = 0; byl < 4; ++byl) {
        const int by = byh * 4 + byl;
        const int row0 = by * 128;
        const signed char* gA =
            Ab + (long)(row0 + wid * 32 + l8) * lda + cs;

        int4v acc[4][4];
#pragma unroll
        for (int m = 0; m < 4; ++m)
#pragma unroll
            for (int n = 0; n < 4; ++n)
#pragma unroll
                for (int j = 0; j < 4; ++j) acc[m][n][j] = 0;

#pragma unroll 1
        for (int kt = 0; kt < 4; ++kt) {
            const int kk = kt * 128;
#pragma unroll
            for (int i = 0; i < 4; ++i)
                llds16(gA + (long)i * 8 * lda + kk, ldsA + i * 1024);
            __syncthreads();  // drains vmcnt: A chunk (+B panel on 1st pass)
            int4v av[4][2], bv[4][2];
#pragma unroll
            for (int m = 0; m < 4; ++m) {
                const int ro = (wr * 64 + m * 16 + lr) * 128;
                av[m][0] = *(const int4v*)&As[ro + uS0];
                av[m][1] = *(const int4v*)&As[ro + uS1];
            }
#pragma unroll
            for (int n = 0; n < 4; ++n) {
                const int ro = (wc * 64 + n * 16 + lr) * 512 + kk;
                bv[n][0] = *(const int4v*)&Bs[ro + uS0];
                bv[n][1] = *(const int4v*)&Bs[ro + uS1];
            }
#pragma unroll
            for (int s = 0; s < 2; ++s)
#pragma unroll
                for (int m = 0; m < 4; ++m)
#pragma unroll
                    for (int n = 0; n < 4; ++n)
                        acc[m][n] = __builtin_amdgcn_mfma_i32_16x16x64_i8(
                            av[m][s], bv[n][s], acc[m][n], 0, 0, 0);
            __syncthreads();  // all reads of As done before next overwrite
        }

        if (IM == 1) {
            const float dq = 1.52587890625e-5f;  // 2^-16
            const int hrow0 = bz * 1024 + row0 + wr * 64;
            const bool diagblk = (bx == by) && (wr == wc);
#pragma unroll
            for (int m = 0; m < 4; ++m) {
                float es[4] = {0.f, 0.f, 0.f, 0.f};
#pragma unroll
                for (int n = 0; n < 4; ++n) {
#pragma unroll
                    for (int j = 0; j < 4; ++j) {
                        const float e = __expf((float)acc[m][n][j] * dq);
                        es[j] += e;
                        if (diagblk && n == m && lr == kg * 4 + j)
                            ddiag[hrow0 + m * 16 + kg * 4 + j] = e;
                    }
                }
#pragma unroll
                for (int j = 0; j < 4; ++j) {
                    float s = es[j];
                    s += __shfl_xor(s, 1, 64);
                    s += __shfl_xor(s, 2, 64);
                    s += __shfl_xor(s, 4, 64);
                    s += __shfl_xor(s, 8, 64);
                    if (lr == 0)
                        atomicAdd(&dsum[hrow0 + m * 16 + kg * 4 + j], s);
                }
            }
        } else {
            const int gbase = col0 + wc * 64 + lr * 4;
            const float s = (bz == 0) ? invs2048 : 128.f;
            const long off = (bz == 0) ? 0 : (long)16777216;
#pragma unroll
            for (int m = 0; m < 4; ++m) {
                const int grow = row0 + wr * 64 + m * 16 + kg * 4;
#pragma unroll
                for (int j = 0; j < 4; ++j) {
                    unsigned int o = 0;
#pragma unroll
                    for (int n = 0; n < 4; ++n) {
                        const float v =
                            (float)acc[m][n][j] * 1.52587890625e-5f;
                        o |= (unsigned int)(unsigned char)q8(v, s) << (8 * n);
                    }
                    *(unsigned int*)(o8 + off + (long)(grow + j) * 4096 +
                                     gbase) = o;
                }
            }
        }
    }
}

// ---------------------------------------------------------------------------
// INT8 GEMM template (unchanged r15 structure) for F1 / FF.
// IM=2 F1 : grid (16,32,1). f1q8 = q8(relu(acc*2^-15 + bias[orig col]), 64).
// IM=3 FF : grid (4,32,4) splitK Kc=512; ffp bf16 partials, packed+perm.
// ---------------------------------------------------------------------------
template <int IM>
__global__ __launch_bounds__(256) void gemm_i8(
    const signed char* __restrict__ Abase,
    const signed char* __restrict__ Bbase,
    signed char* __restrict__ o8,
    unsigned short* __restrict__ o16,
    const float* __restrict__ bias) {
    __shared__ signed char As[128 * 128];
    __shared__ signed char Bs[128 * 128];

    const unsigned gx = gridDim.x, gy = gridDim.y;
    const unsigned nwg = gx * gy * gridDim.z;
    unsigned flat = blockIdx.x + gx * (blockIdx.y + gy * blockIdx.z);
    flat = (flat & 7u) * (nwg >> 3) + (flat >> 3);
    const int bx = flat % gx;
    const int by = (flat / gx) % gy;
    const int bz = flat / (gx * gy);

    const int tid = threadIdx.x;
    const int wid = tid >> 6;
    const int lane = tid & 63;
    const int lr = lane & 15;
    const int kg = lane >> 4;
    const int wr = wid >> 1;
    const int wc = wid & 1;
    const int row0 = by * 128;
    const int col0 = bx * 128;

    int lda, ldb, k0 = 0;
    const signed char* Ab = Abase;
    const signed char* Bb = Bbase;
    if (IM == 2) {
        lda = 512; ldb = 512;
    } else {
        lda = 2048; ldb = 2048;
        k0 = bz * 512;
    }

    const int l8 = lane >> 3;
    const int cs = ((lane & 7) ^ l8) * 16;
    signed char* ldsA = &As[wid * 4096];
    signed char* ldsB = &Bs[wid * 4096];
    const signed char* gA = Ab + (long)(row0 + wid * 32 + l8) * lda + k0 + cs;
    const signed char* gB = Bb + (long)(col0 + wid * 32 + l8) * ldb + k0 + cs;

    const int lr7 = lr & 7;
    const int uS0 = ((0 + kg) ^ lr7) * 16;
    const int uS1 = ((4 + kg) ^ lr7) * 16;

    int4v acc[4][4];
#pragma unroll
    for (int m = 0; m < 4; ++m)
#pragma unroll
        for (int n = 0; n < 4; ++n)
#pragma unroll
            for (int j = 0; j < 4; ++j) acc[m][n][j] = 0;

    for (int kt = 0; kt < 4; ++kt) {
        const int kk = kt * 128;
        __syncthreads();
#pragma unroll
        for (int i = 0; i < 4; ++i) {
            llds16(gA + (long)i * 8 * lda + kk, ldsA + i * 1024);
            llds16(gB + (long)i * 8 * ldb + kk, ldsB + i * 1024);
        }
        __syncthreads();
        int4v av[4][2], bv[4][2];
#pragma unroll
        for (int m = 0; m < 4; ++m) {
            const int ro = (wr * 64 + m * 16 + lr) * 128;
            av[m][0] = *(const int4v*)&As[ro + uS0];
            av[m][1] = *(const int4v*)&As[ro + uS1];
        }
#pragma unroll
        for (int n = 0; n < 4; ++n) {
            const int ro = (wc * 64 + n * 16 + lr) * 128;
            bv[n][0] = *(const int4v*)&Bs[ro + uS0];
            bv[n][1] = *(const int4v*)&Bs[ro + uS1];
        }
#pragma unroll
        for (int s = 0; s < 2; ++s)
#pragma unroll
            for (int m = 0; m < 4; ++m)
#pragma unroll
                for (int n = 0; n < 4; ++n)
                    acc[m][n] = __builtin_amdgcn_mfma_i32_16x16x64_i8(
                        av[m][s], bv[n][s], acc[m][n], 0, 0, 0);
    }

    const int gbase = col0 + wc * 64 + lr * 4;
#pragma unroll
    for (int m = 0; m < 4; ++m) {
        const int grow = row0 + wr * 64 + m * 16 + kg * 4;
#pragma unroll
        for (int j = 0; j < 4; ++j) {
            if (IM == 2) {
                unsigned int o = 0;
#pragma unroll
                for (int n = 0; n < 4; ++n) {
                    const int ocol = col0 + wc * 64 + n * 16 + lr;
                    const float v = fmaxf(
                        fmaf((float)acc[m][n][j], 3.0517578125e-5f,
                             bias[ocol]), 0.f);
                    o |= (unsigned int)(unsigned char)q8(v, 64.f) << (8 * n);
                }
                *(unsigned int*)(o8 + (long)(grow + j) * 2048 + gbase) = o;
            } else {
                const float v0 = (float)acc[m][0][j] * 1.52587890625e-5f;
                const float v1 = (float)acc[m][1][j] * 1.52587890625e-5f;
                const float v2 = (float)acc[m][2][j] * 1.52587890625e-5f;
                const float v3 = (float)acc[m][3][j] * 1.52587890625e-5f;
                uint2 o;
                o.x = (unsigned int)f2bf(v0) | ((unsigned int)f2bf(v1) << 16);
                o.y = (unsigned int)f2bf(v2) | ((unsigned int)f2bf(v3) << 16);
                *(uint2*)(o16 + (long)bz * 2097152 + (long)(grow + j) * 512 +
                          gbase) = o;
            }
        }
    }
}

// ---------------------------------------------------------------------------
// LN reduce helper (rows of 512, 256 threads, 2 cols/thread).
// ---------------------------------------------------------------------------
__device__ __forceinline__ void ln_reduce(float v0, float v1, int tid,
                                          float* sred, float* sred2,
                                          float& mu, float& rs) {
    float sum = v0 + v1;
    float sq = v0 * v0 + v1 * v1;
#pragma unroll
    for (int off = 32; off > 0; off >>= 1) {
        sum += __shfl_down(sum, off, 64);
        sq += __shfl_down(sq, off, 64);
    }
    const int wave = tid >> 6;
    if ((tid & 63) == 0) { sred[wave] = sum; sred2[wave] = sq; }
    __syncthreads();
    if (tid == 0) {
        float s = 0.f, q = 0.f;
#pragma unroll
        for (int w = 0; w < 4; ++w) { s += sred[w]; q += sred2[w]; }
        const float m = s * (1.f / 512.f);
        const float var = q * (1.f / 512.f) - m * m;
        sred[4] = m;
        sred2[4] = rsqrtf(var + LN_EPS);
    }
    __syncthreads();
    mu = sred[4];
    rs = sred2[4];
}

// LN1: y1 = LN(x + sum_a d_a*(Uq/128))*g + be;  y1q = q8(y1, 32).
__global__ __launch_bounds__(256) void ln_combine1(
    const float* __restrict__ x, const signed char* __restrict__ Uq,
    const float* __restrict__ dsum, const float* __restrict__ ddiag,
    const float* __restrict__ g, const float* __restrict__ be,
    float* __restrict__ y1, signed char* __restrict__ y1q) {
    __shared__ float sred[8], sred2[8], df[8];
    const int row = blockIdx.x;
    const int tid = threadIdx.x;
    if (tid < 8) {
        const int b = row >> 10, t = row & 1023;
        const int idx = (b * 8 + tid) * 1024 + t;
        df[tid] = ddiag[idx] / dsum[idx] * (1.f / 128.f);
    }
    __syncthreads();
    const long base = (long)row * 512;
    const long ubase = (long)row * 4096;
    const int p0 = pperm(tid);
    const int p1 = pperm(tid + 256);
    float v0 = x[base + tid];
    float v1 = x[base + tid + 256];
#pragma unroll
    for (int a = 0; a < 8; ++a) {
        const float d = df[a];
        const long ub = ubase + a * 512;
        v0 = fmaf(d, (float)Uq[ub + p0], v0);
        v1 = fmaf(d, (float)Uq[ub + p1], v1);
    }
    float mu, rs;
    ln_reduce(v0, v1, tid, sred, sred2, mu, rs);
    const float o0 = (v0 - mu) * rs * g[tid] + be[tid];
    const float o1 = (v1 - mu) * rs * g[tid + 256] + be[tid + 256];
    y1[base + tid] = o0;
    y1[base + tid + 256] = o1;
    y1q[base + tid] = q8(o0, 32.f);
    y1q[base + tid + 256] = q8(o1, 32.f);
}

// LN2: out = LN(y1 + sum_z ffp_z + bf2)*g + be.  ffp cols K-permuted.
__global__ __launch_bounds__(256) void ln_combine2(
    const float* __restrict__ y1, const unsigned short* __restrict__ ffp,
    const float* __restrict__ bias, const float* __restrict__ g,
    const float* __restrict__ be, float* __restrict__ out) {
    __shared__ float sred[8], sred2[8];
    const int row = blockIdx.x;
    const int tid = threadIdx.x;
    const long base = (long)row * 512;
    const int p0 = pperm(tid);
    const int p1 = pperm(tid + 256);
    float v0 = y1[base + tid] + bias[tid];
    float v1 = y1[base + tid + 256] + bias[tid + 256];
#pragma unroll
    for (int z = 0; z < 4; ++z) {
        const long fb = (long)z * 2097152 + base;
        v0 += bf2f(ffp[fb + p0]);
        v1 += bf2f(ffp[fb + p1]);
    }
    float mu, rs;
    ln_reduce(v0, v1, tid, sred, sred2, mu, rs);
    out[base + tid] = (v0 - mu) * rs * g[tid] + be[tid];
    out[base + tid + 256] = (v1 - mu) * rs * g[tid + 256] + be[tid + 256];
}

// ---------------------------------------------------------------------------
// Launcher
// ---------------------------------------------------------------------------
extern "C" void kernel_launch(void* const* d_in, const int* in_sizes, int n_in,
                              void* d_out, int out_size, void* d_ws, size_t ws_size,
                              hipStream_t stream) {
    const float* x     = (const float*)d_in[0];
    const float* Wq    = (const float*)d_in[1];
    const float* Wk    = (const float*)d_in[2];
    const float* Wv    = (const float*)d_in[3];
    const float* Wo    = (const float*)d_in[4];
    const float* g1    = (const float*)d_in[5];
    const float* beta1 = (const float*)d_in[6];
    const float* Wf1   = (const float*)d_in[7];
    const float* bf1   = (const float*)d_in[8];
    const float* Wf2   = (const float*)d_in[9];
    const float* bf2   = (const float*)d_in[10];
    const float* g2    = (const float*)d_in[11];
    const float* beta2 = (const float*)d_in[12];
    float* out = (float*)d_out;

    char* p = (char*)d_ws;
    unsigned short* Wqb  = (unsigned short*)p; p += (long)512 * 4096 * 2;  // Wqb/Wkb/Wvb contiguous
    unsigned short* Wkb  = (unsigned short*)p; p += (long)512 * 4096 * 2;
    unsigned short* Wvb  = (unsigned short*)p; p += (long)512 * 4096 * 2;
    unsigned short* WoT  = (unsigned short*)p; p += (long)512 * 4096 * 2;
    signed char*  Wf1Tq  = (signed char*)p;    p += (long)2048 * 512;
    signed char*  Wf2Tq  = (signed char*)p;    p += (long)512 * 2048;
    signed char*  Wallq8 = (signed char*)p;    p += (long)8192 * 512;      // W~^T | W^^T i8 (perm K)
    signed char*  PUq8   = (signed char*)p;    p += (long)2 * 4096 * 4096; // P | U i8 (perm cols)
    signed char*  xq8    = (signed char*)p;    p += (long)4096 * 512;      // perm K
    signed char*  y1q8   = (signed char*)p;    p += (long)4096 * 512;
    signed char*  f1q8   = (signed char*)p;    p += (long)4096 * 2048;     // perm cols
    float* dsum  = (float*)p; p += (long)32768 * 4;
    float* ddiag = (float*)p; p += (long)32768 * 4;
    float* y1    = (float*)p; p += (long)4096 * 512 * 4;
    unsigned short* ffp = (unsigned short*)p; p += (long)4 * 4096 * 512 * 2; // bf16 partials (perm cols)

    const dim3 blk(256);
    const float invs = 0.04419417382415922f;  // 1/sqrt(512)
    const int PLDS = 81920;  // 64 KB B panel + 16 KB A chunk

    hipFuncSetAttribute(reinterpret_cast<const void*>(&gemm_pers<0>),
                        hipFuncAttributeMaxDynamicSharedMemorySize, PLDS);
    hipFuncSetAttribute(reinterpret_cast<const void*>(&gemm_pers<1>),
                        hipFuncAttributeMaxDynamicSharedMemorySize, PLDS);

    // 0. fused prologue: converts + x quant + transposes + dsum zero
    prep<<<dim3(9344), blk, 0, stream>>>(Wq, Wk, Wv, Wqb, x, xq8, Wo, WoT,
                                         Wf1, Wf1Tq, Wf2, Wf2Tq, dsum);

    // 1. weight folds -> i8 (s_w = 2^-11), cols K-permuted, one DUAL dispatch
    gemm_fold<<<dim3(4, 4, 16), blk, 0, stream>>>(
        Wkb, Wqb, WoT, Wvb, Wallq8,
        512, 512, 4096, 4096, 512, 512, (long)512 * 512);

    // 2. P = x @ W~all (i8, invs folded), U = x @ W^all (i8 x128)
    //    persistent-B: grid (32 bx, 8 byh, 2 bz), 4 by-tiles per block
    gemm_pers<0><<<dim3(32, 8, 2), blk, PLDS, stream>>>(
        xq8, Wallq8, PUq8, nullptr, nullptr, invs * 2048.f);

    // 3. logits rowsums + diag: per (b,a) P_a[b] @ x_b^T
    //    persistent-B: grid (8 bx, 2 byh, 32 bz), 4 by-tiles per block
    gemm_pers<1><<<dim3(8, 2, 32), blk, PLDS, stream>>>(
        PUq8, xq8, nullptr, dsum, ddiag, 0.f);

    // 4. y1 = LN(x + sum_a d_a U_a)  (+ i8 copy)
    ln_combine1<<<dim3(4096), blk, 0, stream>>>(
        x, PUq8 + (long)16777216, dsum, ddiag, g1, beta1, y1, y1q8);

    // 5. f1 = relu(y1 @ Wf1 + bf1)  (i8 out, x64, perm cols)
    gemm_i8<2><<<dim3(16, 32, 1), blk, 0, stream>>>(
        y1q8, Wf1Tq, f1q8, nullptr, bf1);

    // 6. ffp_z = f1 @ Wf2 partials (split-K x4, Kc=512; bias folded into LN2)
    gemm_i8<3><<<dim3(4, 32, 4), blk, 0, stream>>>(
        f1q8, Wf2Tq, nullptr, ffp, nullptr);

    // 7. out = LN(y1 + sum_z ffp_z + bf2)
    ln_combine2<<<dim3(4096), blk, 0, stream>>>(y1, ffp, bf2, g2, beta2, out);
}

// Round 20
// 123.715 us; speedup vs baseline: 1.0340x; 1.0340x over previous
//
#include <hip/hip_runtime.h>
#include <stdint.h>

// ---------------------------------------------------------------------------
// H=512, N=8, B=4, T=1024.   (ROUND 18 CONFIGURATION — best measured, 124 µs)
// bf16 GEMM (weight folds): 128x128 tile, BK=64, 4 waves, 16x16x32 MFMA,
// global_load_lds width-16 staging, pre-swizzled source + XOR-swizzled
// ds_read (T2 both-sides), single-buffer 2-barrier loop.
// INT8 GEMMs (P/U, logits, f1, ffp): same structure, 128-BYTE K-tiles
// (4 iters per 512-K chunk), mfma_i32_16x16x64_i8, LDS 32 KiB,
// T1 XCD-chunked flat-block remap (LG: 4 whole heads per XCD in L2).
// K-PERMUTED STORAGE: within every 64-byte column group, position w holds
// original column (w&3)*16 + (w>>2).  Applied to BOTH operands of every i8
// GEMM (dot unchanged, integer-exact); epilogues pack 4 n-frag bytes into
// one dword store.
// Quant scales: x ->2^-5, W~/W^ ->2^-11, P ->2^-11 (invs folded),
//   U ->2^-7, y1 ->2^-5, Wf1T/Wf2T ->2^-10, f1 ->2^-6.
// Algebraic folds (per-head H x H): logits_a = x (Wq_a Wk_a^T) x^T -> W~_a;
//   (d o V)@Wo = sum_a d_a x(Wv_a Wo_a) -> W^_a; d_a folded into LN1.
// Logits epilogue: exp + row-sums + diagonal.  Wf2 split-K x4 bf16 partials.
// Fused prologue `prep` (converts + x quant + transposes + dsum zero).
// ---------------------------------------------------------------------------

#define LN_EPS 1e-5f

typedef __attribute__((ext_vector_type(8))) short short8;
typedef __attribute__((ext_vector_type(4))) float f32x4;
typedef __attribute__((ext_vector_type(4))) int int4v;

__device__ __forceinline__ unsigned short f2bf(float f) {
    unsigned int u = __float_as_uint(f);
    u = (u + 0x7fffu + ((u >> 16) & 1u)) >> 16;
    return (unsigned short)u;
}
__device__ __forceinline__ float bf2f(unsigned short h) {
    return __uint_as_float(((unsigned int)h) << 16);
}
__device__ __forceinline__ signed char q8(float v, float s) {
    int q = (int)rintf(v * s);
    q = q > 127 ? 127 : (q < -127 ? -127 : q);
    return (signed char)q;
}
// permuted position of original within-64 index w
__device__ __forceinline__ int pperm(int w) {
    return (w & ~63) + ((w & 15) << 2) + ((w >> 4) & 3);
}

__device__ __forceinline__ void llds16(const void* g, void* l) {
    __builtin_amdgcn_global_load_lds(
        (const __attribute__((address_space(1))) void*)g,
        (__attribute__((address_space(3))) void*)l, 16, 0, 0);
}

// ---------------------------------------------------------------------------
// PREP: fused prologue.  Flat-bid ranges:
//  [0,3072) convert Wq/Wk/Wv->bf16; [3072,5120) quant_x_perm;
//  [5120,7168) transpose Wo->bf16; [7168,8192) transpose Wf1->i8;
//  [8192,9216) transpose Wf2->i8 (perm dst); [9216,9344) zero dsum.
// ---------------------------------------------------------------------------
__global__ __launch_bounds__(256) void prep(
    const float* __restrict__ Wq, const float* __restrict__ Wk,
    const float* __restrict__ Wv, unsigned short* __restrict__ Wqb,
    const float* __restrict__ x, signed char* __restrict__ xq,
    const float* __restrict__ Wo, unsigned short* __restrict__ WoT,
    const float* __restrict__ Wf1, signed char* __restrict__ Wf1Tq,
    const float* __restrict__ Wf2, signed char* __restrict__ Wf2Tq,
    float* __restrict__ dsum) {
    __shared__ float tile[32][33];
    const int bid = blockIdx.x;
    const int tid = threadIdx.x;

    if (bid < 3072) {
        const int y = bid >> 10;
        const int idx = (bid & 1023) * 256 + tid;
        const float* src = (y == 0) ? Wq : (y == 1) ? Wk : Wv;
        float4 a = ((const float4*)src)[idx * 2];
        float4 b = ((const float4*)src)[idx * 2 + 1];
        uint4 o;
        o.x = (unsigned int)f2bf(a.x) | ((unsigned int)f2bf(a.y) << 16);
        o.y = (unsigned int)f2bf(a.z) | ((unsigned int)f2bf(a.w) << 16);
        o.z = (unsigned int)f2bf(b.x) | ((unsigned int)f2bf(b.y) << 16);
        o.w = (unsigned int)f2bf(b.z) | ((unsigned int)f2bf(b.w) << 16);
        ((uint4*)(Wqb + (long)y * 2097152))[idx] = o;
    } else if (bid < 5120) {
        const int idx = (bid - 3072) * 256 + tid;
        const int t = idx >> 7;
        const int rem = idx & 127;
        const int g = rem >> 4, lr = rem & 15;
        const long rb = (long)t * 512 + g * 64;
        unsigned int o = 0;
#pragma unroll
        for (int n = 0; n < 4; ++n)
            o |= (unsigned int)(unsigned char)q8(x[rb + n * 16 + lr], 32.f)
                 << (8 * n);
        *(unsigned int*)(xq + rb + lr * 4) = o;
    } else if (bid < 7168) {
        const int r = bid - 5120;
        const int bx = r & 15, by = r >> 4;
        const int tx = tid & 31, ty = tid >> 5;
        const int r0 = by * 32, c0 = bx * 32;
        const int R = 4096, C = 512;
#pragma unroll
        for (int k = 0; k < 4; ++k)
            tile[ty + k * 8][tx] = Wo[(long)(r0 + ty + k * 8) * C + c0 + tx];
        __syncthreads();
#pragma unroll
        for (int k = 0; k < 4; ++k)
            WoT[(long)(c0 + ty + k * 8) * R + r0 + tx] =
                f2bf(tile[tx][ty + k * 8]);
    } else if (bid < 8192) {
        const int r = bid - 7168;
        const int bx = r & 63, by = r >> 6;
        const int tx = tid & 31, ty = tid >> 5;
        const int r0 = by * 32, c0 = bx * 32;
        const int R = 512, C = 2048;
#pragma unroll
        for (int k = 0; k < 4; ++k)
            tile[ty + k * 8][tx] = Wf1[(long)(r0 + ty + k * 8) * C + c0 + tx];
        __syncthreads();
#pragma unroll
        for (int k = 0; k < 4; ++k)
            Wf1Tq[(long)(c0 + ty + k * 8) * R + (r0 + tx)] =
                q8(tile[tx][ty + k * 8], 1024.f);
    } else if (bid < 9216) {
        const int r = bid - 8192;
        const int bx = r & 15, by = r >> 4;
        const int tx = tid & 31, ty = tid >> 5;
        const int r0 = by * 32, c0 = bx * 32;
        const int R = 2048, C = 512;
#pragma unroll
        for (int k = 0; k < 4; ++k)
            tile[ty + k * 8][tx] = Wf2[(long)(r0 + ty + k * 8) * C + c0 + tx];
        __syncthreads();
#pragma unroll
        for (int k = 0; k < 4; ++k) {
            const int rr = r0 + tx;
            Wf2Tq[(long)(c0 + ty + k * 8) * R + pperm(rr)] =
                q8(tile[tx][ty + k * 8], 1024.f);
        }
    } else {
        const int idx = (bid - 9216) * 256 + tid;
        dsum[idx] = 0.f;
    }
}

// ---------------------------------------------------------------------------
// bf16 MFMA GEMM (weight folds).  DUAL: bz = f*8+a.  Output i8, cols
// K-permuted + dword-packed.
// ---------------------------------------------------------------------------
__global__ __launch_bounds__(256) void gemm_fold(
    const unsigned short* __restrict__ A,
    const unsigned short* __restrict__ Bt,
    const unsigned short* __restrict__ A2,
    const unsigned short* __restrict__ B2,
    signed char* __restrict__ Cv,
    int N, int K, int lda, int ldb,
    long aBatch, long bBatch, long cBatch) {
    __shared__ unsigned short As[128 * 64];
    __shared__ unsigned short Bs[128 * 64];

    const int bx = blockIdx.x, by = blockIdx.y, bz = blockIdx.z;
    const int tid = threadIdx.x;
    const int wid = tid >> 6;
    const int lane = tid & 63;
    const int lr = lane & 15;
    const int kg = lane >> 4;
    const int wr = wid >> 1;
    const int wc = wid & 1;
    const int row0 = by * 128;
    const int col0 = bx * 128;

    const int zf = bz >> 3, za = bz & 7;
    const unsigned short* Ab = (zf ? A2 : A) + (long)za * aBatch;
    const unsigned short* Bb = (zf ? B2 : Bt) + (long)za * bBatch;
    const long cOff = (long)bz * cBatch;

    const int l8 = lane >> 3;
    const int cs = ((lane & 7) ^ l8) * 8;
    unsigned short* ldsA = &As[wid * 2048];
    unsigned short* ldsB = &Bs[wid * 2048];
    const unsigned short* gA = Ab + (long)(row0 + wid * 32 + l8) * lda + cs;
    const unsigned short* gB = Bb + (long)(col0 + wid * 32 + l8) * ldb + cs;

    const int lr7 = lr & 7;
    const int uS0 = ((0 + kg) ^ lr7) * 8;
    const int uS1 = ((4 + kg) ^ lr7) * 8;

    f32x4 acc[4][4];
#pragma unroll
    for (int m = 0; m < 4; ++m)
#pragma unroll
        for (int n = 0; n < 4; ++n)
#pragma unroll
            for (int j = 0; j < 4; ++j) acc[m][n][j] = 0.f;

    for (int kk = 0; kk < K; kk += 64) {
        __syncthreads();
#pragma unroll
        for (int i = 0; i < 4; ++i) {
            llds16(gA + (long)i * 8 * lda + kk, ldsA + i * 512);
            llds16(gB + (long)i * 8 * ldb + kk, ldsB + i * 512);
        }
        __syncthreads();
        short8 a[4][2], b[4][2];
#pragma unroll
        for (int m = 0; m < 4; ++m) {
            const int ro = (wr * 64 + m * 16 + lr) * 64;
            a[m][0] = *(const short8*)&As[ro + uS0];
            a[m][1] = *(const short8*)&As[ro + uS1];
        }
#pragma unroll
        for (int n = 0; n < 4; ++n) {
            const int ro = (wc * 64 + n * 16 + lr) * 64;
            b[n][0] = *(const short8*)&Bs[ro + uS0];
            b[n][1] = *(const short8*)&Bs[ro + uS1];
        }
#pragma unroll
        for (int s = 0; s < 2; ++s)
#pragma unroll
            for (int m = 0; m < 4; ++m)
#pragma unroll
                for (int n = 0; n < 4; ++n)
                    acc[m][n] = __builtin_amdgcn_mfma_f32_16x16x32_bf16(
                        a[m][s], b[n][s], acc[m][n], 0, 0, 0);
    }

    const int gbase = col0 + wc * 64 + lr * 4;
#pragma unroll
    for (int m = 0; m < 4; ++m) {
        const int grow = row0 + wr * 64 + m * 16 + kg * 4;
#pragma unroll
        for (int j = 0; j < 4; ++j) {
            unsigned int o = 0;
#pragma unroll
            for (int n = 0; n < 4; ++n)
                o |= (unsigned int)(unsigned char)q8(acc[m][n][j], 2048.f)
                     << (8 * n);
            *(unsigned int*)(Cv + cOff + (long)(grow + j) * N + gbase) = o;
        }
    }
}

// ---------------------------------------------------------------------------
// INT8 GEMM template (128x128 tile, 128-byte K-tiles, 4 iters,
// mfma_i32_16x16x64_i8), LDS 32 KiB, T1 XCD-chunked block remap.
// All i8 operands K-PERMUTED (both sides -> dot unchanged).
// IM=0 PU : grid (32,32,2). A=xq8 [4096][512]p; B=Wallq8+bz*4096*512 p.
//           bz0 -> Pq8 (q8 x invs2048), bz1 -> U i8 (q8 x128).
// IM=1 LG : grid (8,8,32). A=Pq8+b*1024*4096+a*512 (p), B=xq8+b*... (p);
//           epilogue exp(acc*2^-16) -> dsum/ddiag.
// IM=2 F1 : grid (16,32,1). f1q8 = q8(relu(acc*2^-15 + bias[orig col]), 64).
// IM=3 FF : grid (4,32,4) splitK Kc=512; ffp bf16 partials, packed+perm.
// ---------------------------------------------------------------------------
template <int IM>
__global__ __launch_bounds__(256) void gemm_i8(
    const signed char* __restrict__ Abase,
    const signed char* __restrict__ Bbase,
    signed char* __restrict__ o8,
    unsigned short* __restrict__ o16,
    const float* __restrict__ bias,
    float* __restrict__ dsum, float* __restrict__ ddiag,
    float invs2048) {
    __shared__ signed char As[128 * 128];
    __shared__ signed char Bs[128 * 128];

    // T1 XCD-chunked remap (all grids are multiples of 8 blocks)
    const unsigned gx = gridDim.x, gy = gridDim.y;
    const unsigned nwg = gx * gy * gridDim.z;
    unsigned flat = blockIdx.x + gx * (blockIdx.y + gy * blockIdx.z);
    flat = (flat & 7u) * (nwg >> 3) + (flat >> 3);
    const int bx = flat % gx;
    const int by = (flat / gx) % gy;
    const int bz = flat / (gx * gy);

    const int tid = threadIdx.x;
    const int wid = tid >> 6;
    const int lane = tid & 63;
    const int lr = lane & 15;
    const int kg = lane >> 4;
    const int wr = wid >> 1;
    const int wc = wid & 1;
    const int row0 = by * 128;
    const int col0 = bx * 128;

    int lda, ldb, k0 = 0;
    const signed char* Ab;
    const signed char* Bb;
    if (IM == 0) {
        lda = 512; ldb = 512;
        Ab = Abase;
        Bb = Bbase + (long)bz * (4096 * 512);
    } else if (IM == 1) {
        lda = 4096; ldb = 512;
        const int b = bz >> 3, a = bz & 7;
        Ab = Abase + (long)b * (1024 * 4096) + a * 512;
        Bb = Bbase + (long)b * (1024 * 512);
    } else if (IM == 2) {
        lda = 512; ldb = 512;
        Ab = Abase; Bb = Bbase;
    } else {
        lda = 2048; ldb = 2048;
        Ab = Abase; Bb = Bbase;
        k0 = bz * 512;
    }

    const int l8 = lane >> 3;
    const int cs = ((lane & 7) ^ l8) * 16;
    signed char* ldsA = &As[wid * 4096];
    signed char* ldsB = &Bs[wid * 4096];
    const signed char* gA = Ab + (long)(row0 + wid * 32 + l8) * lda + k0 + cs;
    const signed char* gB = Bb + (long)(col0 + wid * 32 + l8) * ldb + k0 + cs;

    const int lr7 = lr & 7;
    const int uS0 = ((0 + kg) ^ lr7) * 16;
    const int uS1 = ((4 + kg) ^ lr7) * 16;

    int4v acc[4][4];
#pragma unroll
    for (int m = 0; m < 4; ++m)
#pragma unroll
        for (int n = 0; n < 4; ++n)
#pragma unroll
            for (int j = 0; j < 4; ++j) acc[m][n][j] = 0;

    for (int kt = 0; kt < 4; ++kt) {
        const int kk = kt * 128;
        __syncthreads();
#pragma unroll
        for (int i = 0; i < 4; ++i) {
            llds16(gA + (long)i * 8 * lda + kk, ldsA + i * 1024);
            llds16(gB + (long)i * 8 * ldb + kk, ldsB + i * 1024);
        }
        __syncthreads();
        int4v av[4][2], bv[4][2];
#pragma unroll
        for (int m = 0; m < 4; ++m) {
            const int ro = (wr * 64 + m * 16 + lr) * 128;
            av[m][0] = *(const int4v*)&As[ro + uS0];
            av[m][1] = *(const int4v*)&As[ro + uS1];
        }
#pragma unroll
        for (int n = 0; n < 4; ++n) {
            const int ro = (wc * 64 + n * 16 + lr) * 128;
            bv[n][0] = *(const int4v*)&Bs[ro + uS0];
            bv[n][1] = *(const int4v*)&Bs[ro + uS1];
        }
#pragma unroll
        for (int s = 0; s < 2; ++s)
#pragma unroll
            for (int m = 0; m < 4; ++m)
#pragma unroll
                for (int n = 0; n < 4; ++n)
                    acc[m][n] = __builtin_amdgcn_mfma_i32_16x16x64_i8(
                        av[m][s], bv[n][s], acc[m][n], 0, 0, 0);
    }

    if (IM == 1) {
        const float dq = 1.52587890625e-5f;  // 2^-16
        const int hrow0 = bz * 1024 + row0 + wr * 64;
        const bool diagblk = (bx == by) && (wr == wc);
#pragma unroll
        for (int m = 0; m < 4; ++m) {
            float es[4] = {0.f, 0.f, 0.f, 0.f};
#pragma unroll
            for (int n = 0; n < 4; ++n) {
#pragma unroll
                for (int j = 0; j < 4; ++j) {
                    const float e = __expf((float)acc[m][n][j] * dq);
                    es[j] += e;
                    if (diagblk && n == m && lr == kg * 4 + j)
                        ddiag[hrow0 + m * 16 + kg * 4 + j] = e;
                }
            }
#pragma unroll
            for (int j = 0; j < 4; ++j) {
                float s = es[j];
                s += __shfl_xor(s, 1, 64);
                s += __shfl_xor(s, 2, 64);
                s += __shfl_xor(s, 4, 64);
                s += __shfl_xor(s, 8, 64);
                if (lr == 0) atomicAdd(&dsum[hrow0 + m * 16 + kg * 4 + j], s);
            }
        }
        return;
    }

    const int gbase = col0 + wc * 64 + lr * 4;  // permuted dword base
#pragma unroll
    for (int m = 0; m < 4; ++m) {
        const int grow = row0 + wr * 64 + m * 16 + kg * 4;
#pragma unroll
        for (int j = 0; j < 4; ++j) {
            if (IM == 0) {
                unsigned int o = 0;
                const float s = (bz == 0) ? invs2048 : 128.f;
#pragma unroll
                for (int n = 0; n < 4; ++n) {
                    const float v = (float)acc[m][n][j] * 1.52587890625e-5f;
                    o |= (unsigned int)(unsigned char)q8(v, s) << (8 * n);
                }
                const long off = (bz == 0) ? 0 : (long)16777216;
                *(unsigned int*)(o8 + off + (long)(grow + j) * 4096 + gbase) = o;
            } else if (IM == 2) {
                unsigned int o = 0;
#pragma unroll
                for (int n = 0; n < 4; ++n) {
                    const int ocol = col0 + wc * 64 + n * 16 + lr;
                    const float v = fmaxf(
                        fmaf((float)acc[m][n][j], 3.0517578125e-5f,
                             bias[ocol]), 0.f);
                    o |= (unsigned int)(unsigned char)q8(v, 64.f) << (8 * n);
                }
                *(unsigned int*)(o8 + (long)(grow + j) * 2048 + gbase) = o;
            } else {
                const float v0 = (float)acc[m][0][j] * 1.52587890625e-5f;
                const float v1 = (float)acc[m][1][j] * 1.52587890625e-5f;
                const float v2 = (float)acc[m][2][j] * 1.52587890625e-5f;
                const float v3 = (float)acc[m][3][j] * 1.52587890625e-5f;
                uint2 o;
                o.x = (unsigned int)f2bf(v0) | ((unsigned int)f2bf(v1) << 16);
                o.y = (unsigned int)f2bf(v2) | ((unsigned int)f2bf(v3) << 16);
                *(uint2*)(o16 + (long)bz * 2097152 + (long)(grow + j) * 512 +
                          gbase) = o;
            }
        }
    }
}

// ---------------------------------------------------------------------------
// LN reduce helper (rows of 512, 256 threads, 2 cols/thread).
// ---------------------------------------------------------------------------
__device__ __forceinline__ void ln_reduce(float v0, float v1, int tid,
                                          float* sred, float* sred2,
                                          float& mu, float& rs) {
    float sum = v0 + v1;
    float sq = v0 * v0 + v1 * v1;
#pragma unroll
    for (int off = 32; off > 0; off >>= 1) {
        sum += __shfl_down(sum, off, 64);
        sq += __shfl_down(sq, off, 64);
    }
    const int wave = tid >> 6;
    if ((tid & 63) == 0) { sred[wave] = sum; sred2[wave] = sq; }
    __syncthreads();
    if (tid == 0) {
        float s = 0.f, q = 0.f;
#pragma unroll
        for (int w = 0; w < 4; ++w) { s += sred[w]; q += sred2[w]; }
        const float m = s * (1.f / 512.f);
        const float var = q * (1.f / 512.f) - m * m;
        sred[4] = m;
        sred2[4] = rsqrtf(var + LN_EPS);
    }
    __syncthreads();
    mu = sred[4];
    rs = sred2[4];
}

// LN1: y1 = LN(x + sum_a d_a*(Uq/128))*g + be;  y1q = q8(y1, 32).
__global__ __launch_bounds__(256) void ln_combine1(
    const float* __restrict__ x, const signed char* __restrict__ Uq,
    const float* __restrict__ dsum, const float* __restrict__ ddiag,
    const float* __restrict__ g, const float* __restrict__ be,
    float* __restrict__ y1, signed char* __restrict__ y1q) {
    __shared__ float sred[8], sred2[8], df[8];
    const int row = blockIdx.x;
    const int tid = threadIdx.x;
    if (tid < 8) {
        const int b = row >> 10, t = row & 1023;
        const int idx = (b * 8 + tid) * 1024 + t;
        df[tid] = ddiag[idx] / dsum[idx] * (1.f / 128.f);
    }
    __syncthreads();
    const long base = (long)row * 512;
    const long ubase = (long)row * 4096;
    const int p0 = pperm(tid);
    const int p1 = pperm(tid + 256);
    float v0 = x[base + tid];
    float v1 = x[base + tid + 256];
#pragma unroll
    for (int a = 0; a < 8; ++a) {
        const float d = df[a];
        const long ub = ubase + a * 512;
        v0 = fmaf(d, (float)Uq[ub + p0], v0);
        v1 = fmaf(d, (float)Uq[ub + p1], v1);
    }
    float mu, rs;
    ln_reduce(v0, v1, tid, sred, sred2, mu, rs);
    const float o0 = (v0 - mu) * rs * g[tid] + be[tid];
    const float o1 = (v1 - mu) * rs * g[tid + 256] + be[tid + 256];
    y1[base + tid] = o0;
    y1[base + tid + 256] = o1;
    y1q[base + tid] = q8(o0, 32.f);
    y1q[base + tid + 256] = q8(o1, 32.f);
}

// LN2: out = LN(y1 + sum_z ffp_z + bf2)*g + be.  ffp cols K-permuted.
__global__ __launch_bounds__(256) void ln_combine2(
    const float* __restrict__ y1, const unsigned short* __restrict__ ffp,
    const float* __restrict__ bias, const float* __restrict__ g,
    const float* __restrict__ be, float* __restrict__ out) {
    __shared__ float sred[8], sred2[8];
    const int row = blockIdx.x;
    const int tid = threadIdx.x;
    const long base = (long)row * 512;
    const int p0 = pperm(tid);
    const int p1 = pperm(tid + 256);
    float v0 = y1[base + tid] + bias[tid];
    float v1 = y1[base + tid + 256] + bias[tid + 256];
#pragma unroll
    for (int z = 0; z < 4; ++z) {
        const long fb = (long)z * 2097152 + base;
        v0 += bf2f(ffp[fb + p0]);
        v1 += bf2f(ffp[fb + p1]);
    }
    float mu, rs;
    ln_reduce(v0, v1, tid, sred, sred2, mu, rs);
    out[base + tid] = (v0 - mu) * rs * g[tid] + be[tid];
    out[base + tid + 256] = (v1 - mu) * rs * g[tid + 256] + be[tid + 256];
}

// ---------------------------------------------------------------------------
// Launcher
// ---------------------------------------------------------------------------
extern "C" void kernel_launch(void* const* d_in, const int* in_sizes, int n_in,
                              void* d_out, int out_size, void* d_ws, size_t ws_size,
                              hipStream_t stream) {
    const float* x     = (const float*)d_in[0];
    const float* Wq    = (const float*)d_in[1];
    const float* Wk    = (const float*)d_in[2];
    const float* Wv    = (const float*)d_in[3];
    const float* Wo    = (const float*)d_in[4];
    const float* g1    = (const float*)d_in[5];
    const float* beta1 = (const float*)d_in[6];
    const float* Wf1   = (const float*)d_in[7];
    const float* bf1   = (const float*)d_in[8];
    const float* Wf2   = (const float*)d_in[9];
    const float* bf2   = (const float*)d_in[10];
    const float* g2    = (const float*)d_in[11];
    const float* beta2 = (const float*)d_in[12];
    float* out = (float*)d_out;

    char* p = (char*)d_ws;
    unsigned short* Wqb  = (unsigned short*)p; p += (long)512 * 4096 * 2;  // Wqb/Wkb/Wvb contiguous
    unsigned short* Wkb  = (unsigned short*)p; p += (long)512 * 4096 * 2;
    unsigned short* Wvb  = (unsigned short*)p; p += (long)512 * 4096 * 2;
    unsigned short* WoT  = (unsigned short*)p; p += (long)512 * 4096 * 2;
    signed char*  Wf1Tq  = (signed char*)p;    p += (long)2048 * 512;
    signed char*  Wf2Tq  = (signed char*)p;    p += (long)512 * 2048;
    signed char*  Wallq8 = (signed char*)p;    p += (long)8192 * 512;      // W~^T | W^^T i8 (perm K)
    signed char*  PUq8   = (signed char*)p;    p += (long)2 * 4096 * 4096; // P | U i8 (perm cols)
    signed char*  xq8    = (signed char*)p;    p += (long)4096 * 512;      // perm K
    signed char*  y1q8   = (signed char*)p;    p += (long)4096 * 512;
    signed char*  f1q8   = (signed char*)p;    p += (long)4096 * 2048;     // perm cols
    float* dsum  = (float*)p; p += (long)32768 * 4;
    float* ddiag = (float*)p; p += (long)32768 * 4;
    float* y1    = (float*)p; p += (long)4096 * 512 * 4;
    unsigned short* ffp = (unsigned short*)p; p += (long)4 * 4096 * 512 * 2; // bf16 partials (perm cols)

    const dim3 blk(256);
    const float invs = 0.04419417382415922f;  // 1/sqrt(512)

    // 0. fused prologue: converts + x quant + transposes + dsum zero
    prep<<<dim3(9344), blk, 0, stream>>>(Wq, Wk, Wv, Wqb, x, xq8, Wo, WoT,
                                         Wf1, Wf1Tq, Wf2, Wf2Tq, dsum);

    // 1. weight folds -> i8 (s_w = 2^-11), cols K-permuted, one DUAL dispatch
    gemm_fold<<<dim3(4, 4, 16), blk, 0, stream>>>(
        Wkb, Wqb, WoT, Wvb, Wallq8,
        512, 512, 4096, 4096, 512, 512, (long)512 * 512);

    // 2. P = x @ W~all (i8, invs folded), U = x @ W^all (i8 x128)
    gemm_i8<0><<<dim3(32, 32, 2), blk, 0, stream>>>(
        xq8, Wallq8, PUq8, nullptr, nullptr, nullptr, nullptr, invs * 2048.f);

    // 3. logits rowsums + diag: per (b,a) P_a[b] @ x_b^T
    gemm_i8<1><<<dim3(8, 8, 32), blk, 0, stream>>>(
        PUq8, xq8, nullptr, nullptr, nullptr, dsum, ddiag, 0.f);

    // 4. y1 = LN(x + sum_a d_a U_a)  (+ i8 copy)
    ln_combine1<<<dim3(4096), blk, 0, stream>>>(
        x, PUq8 + (long)16777216, dsum, ddiag, g1, beta1, y1, y1q8);

    // 5. f1 = relu(y1 @ Wf1 + bf1)  (i8 out, x64, perm cols)
    gemm_i8<2><<<dim3(16, 32, 1), blk, 0, stream>>>(
        y1q8, Wf1Tq, f1q8, nullptr, bf1, nullptr, nullptr, 0.f);

    // 6. ffp_z = f1 @ Wf2 partials (split-K x4, Kc=512; bias folded into LN2)
    gemm_i8<3><<<dim3(4, 32, 4), blk, 0, stream>>>(
        f1q8, Wf2Tq, nullptr, ffp, nullptr, nullptr, nullptr, 0.f);

    // 7. out = LN(y1 + sum_z ffp_z + bf2)
    ln_combine2<<<dim3(4096), blk, 0, stream>>>(y1, ffp, bf2, g2, beta2, out);
}